// Round 5
// baseline (920.995 us; speedup 1.0000x reference)
//
#include <hip/hip_runtime.h>
#include <hip/hip_bf16.h>

#define EMB 384
#define NPOS 8193   // 2L+1 state positions
#define LAYERS 12
#define BATCH 4
#define PT 64       // positions per workgroup

typedef __attribute__((ext_vector_type(8))) short bf16x8;
typedef __attribute__((ext_vector_type(4))) float f32x4;
typedef __attribute__((ext_vector_type(4))) unsigned short u16x4;

__device__ __forceinline__ float b2f(unsigned short u) {
    union { unsigned int i; float f; } v; v.i = ((unsigned int)u) << 16; return v.f;
}
__device__ __forceinline__ unsigned short f2b(float f) {
    union { float f; unsigned int i; } v; v.f = f;
    unsigned int x = v.i;
    return (unsigned short)((x + 0x7FFFu + ((x >> 16) & 1u)) >> 16);
}

// ---- weight pre-swizzle: W_swz[layer][kb(36)][nb(24)][lane(64)][8 bf16]
// logical K: 0..383 = w_center, 384..767 = w_right, 768..1151 = w_left
// per 16x32 block: lane holds col n = nb*16 + (lane&15), k = kb*32 + 8*(lane>>4) + e
__global__ void w_prep(const float* __restrict__ wl, const float* __restrict__ wc,
                       const float* __restrict__ wr, unsigned short* __restrict__ wswz) {
    int idx = blockIdx.x * blockDim.x + threadIdx.x;
    const int total = LAYERS * 36 * 24 * 64;
    if (idx >= total) return;
    int lane = idx & 63;
    int t = idx >> 6;
    int nb = t % 24; t /= 24;
    int kb = t % 36; t /= 36;
    int layer = t;
    int seg = kb / 12;
    const float* src = (seg == 0 ? wc : (seg == 1 ? wr : wl)) + (size_t)layer * EMB * EMB;
    int kloc = (kb % 12) * 32 + ((lane >> 4) << 3);
    int n = nb * 16 + (lane & 15);
    unsigned short o[8];
#pragma unroll
    for (int e = 0; e < 8; ++e) o[e] = f2b(src[(size_t)n * EMB + kloc + e]);
    *reinterpret_cast<uint4*>(wswz + (size_t)idx * 8) = *reinterpret_cast<uint4*>(o);
}

// ---- initial state X[b][pos][plane][384] bf16
__global__ void x_init(const float* __restrict__ embs, const float* __restrict__ mask,
                       unsigned short* __restrict__ X) {
    int idx = blockIdx.x * blockDim.x + threadIdx.x;
    const int total = BATCH * NPOS * (EMB / 8);
    if (idx >= total) return;
    int dg = idx % (EMB / 8);
    int t = idx / (EMB / 8);
    int pos = t % NPOS;
    int b = t / NPOS;
    int d0 = dg * 8;
    const float* m = mask + (size_t)b * EMB + d0;
    const float* p0src;
    if (pos >= 1 && pos <= 4096) p0src = embs + ((size_t)b * 4096 + (pos - 1)) * EMB + d0;
    else if (pos == 8192)        p0src = embs + (size_t)b * 4096 * EMB + d0;
    else                         p0src = m;
    unsigned short o0[8], o1[8];
#pragma unroll
    for (int e = 0; e < 8; ++e) { o0[e] = f2b(p0src[e]); o1[e] = f2b(m[e]); }
    size_t base = ((size_t)b * NPOS + pos) * 2 * EMB + d0;
    *reinterpret_cast<uint4*>(X + base)       = *reinterpret_cast<uint4*>(o0);
    *reinterpret_cast<uint4*>(X + base + EMB) = *reinterpret_cast<uint4*>(o1);
}

// LDS X-tile access: 768B rows, XOR bank swizzle (8x16B blocks keyed on row&7)
#define LDSOFF(row, inner) ((row) * 768 + ((inner) ^ (((row) & 7) << 4)))

// ---- one layer, PT=64: y[j,pl] = relu(Wc x[j+1,pl] + Wr x0[j+2] + Wl x0[j] + b) + x[j+1,pl]
// 16 waves = 8 n-slices (48 cols) x 2 position-groups (32 pos).
// Plane0 (+halo) staged in LDS; plane1 center/residual read from global (L2).
// Neighbor term plane-independent: computed once into plane0 accs, copied to plane1 accs.
__global__ __launch_bounds__(1024, 4) void layer_k(
    const unsigned short* __restrict__ Xin, unsigned short* __restrict__ Xout,
    const unsigned short* __restrict__ W, const float* __restrict__ bias) {
    __shared__ char smem[66 * 768];
    const int tid = threadIdx.x;
    const int b = blockIdx.y;
    const int j0 = blockIdx.x * PT;
    const size_t xbase = (size_t)b * NPOS * 2 * EMB;

    // stage plane0 rows: pos j0..j0+65 (clamped)
    for (int idx = tid; idx < 66 * 48; idx += 1024) {
        int row = idx / 48, cg = idx % 48;
        int pos = j0 + row; if (pos > 8192) pos = 8192;
        uint4 v = *reinterpret_cast<const uint4*>(Xin + xbase + (size_t)pos * 2 * EMB + cg * 8);
        *reinterpret_cast<uint4*>(smem + LDSOFF(row, cg * 16)) = v;
    }
    __syncthreads();

    const int lane = tid & 63;
    const int wv = tid >> 6;     // 0..15
    const int ns = wv & 7;       // n-slice: 48 cols
    const int mg = wv >> 3;      // position group: 32 pos
    const int lrow = lane & 15;
    const int g = lane >> 4;
    const int p0 = mg * 32 + lrow;        // local position, m-block 0
    const int p1 = mg * 32 + 16 + lrow;   // local position, m-block 1
    const int nbase = ns * 48;

    const unsigned short* x1r0 = Xin + xbase + ((size_t)(j0 + 1 + p0) * 2 + 1) * EMB;
    const unsigned short* x1r1 = Xin + xbase + ((size_t)(j0 + 1 + p1) * 2 + 1) * EMB;

    f32x4 c00[3], c01[3], c10[3], c11[3];
#pragma unroll
    for (int n = 0; n < 3; ++n) { c00[n] = f32x4{0.f,0.f,0.f,0.f}; c01[n] = f32x4{0.f,0.f,0.f,0.f}; }

    const bf16x8* wb = reinterpret_cast<const bf16x8*>(W) + (size_t)(ns * 3) * 64 + lane;

    // ---- neighbor phase: t 0..11 -> kb 12..23 (right, x0[p+2]); t 12..23 -> kb 24..35 (left, x0[p])
#pragma unroll
    for (int t = 0; t < 24; ++t) {
        const int kb = 12 + t;
        bf16x8 wf[3];
#pragma unroll
        for (int n = 0; n < 3; ++n) wf[n] = wb[(kb * 24 + n) * 64];
        const int d = (t < 12) ? 2 : 0;
        const int inner = (t % 12) * 64 + g * 16;
        bf16x8 xa = *reinterpret_cast<const bf16x8*>(smem + LDSOFF(p0 + d, inner));
        bf16x8 xb = *reinterpret_cast<const bf16x8*>(smem + LDSOFF(p1 + d, inner));
#pragma unroll
        for (int n = 0; n < 3; ++n) {
            c00[n] = __builtin_amdgcn_mfma_f32_16x16x32_bf16(wf[n], xa, c00[n], 0, 0, 0);
            c01[n] = __builtin_amdgcn_mfma_f32_16x16x32_bf16(wf[n], xb, c01[n], 0, 0, 0);
        }
    }
    // copy plane-independent neighbor result to plane1 accumulators
#pragma unroll
    for (int n = 0; n < 3; ++n) { c10[n] = c00[n]; c11[n] = c01[n]; }

    // ---- center phase: kb 0..11; plane0 rows p+1 from LDS, plane1 from global
#pragma unroll
    for (int t = 0; t < 12; ++t) {
        bf16x8 wf[3];
#pragma unroll
        for (int n = 0; n < 3; ++n) wf[n] = wb[(t * 24 + n) * 64];
        const int inner = t * 64 + g * 16;
        bf16x8 x00 = *reinterpret_cast<const bf16x8*>(smem + LDSOFF(p0 + 1, inner));
        bf16x8 x01 = *reinterpret_cast<const bf16x8*>(smem + LDSOFF(p1 + 1, inner));
        bf16x8 x10 = *reinterpret_cast<const bf16x8*>(x1r0 + t * 32 + g * 8);
        bf16x8 x11 = *reinterpret_cast<const bf16x8*>(x1r1 + t * 32 + g * 8);
#pragma unroll
        for (int n = 0; n < 3; ++n) {
            c00[n] = __builtin_amdgcn_mfma_f32_16x16x32_bf16(wf[n], x00, c00[n], 0, 0, 0);
            c01[n] = __builtin_amdgcn_mfma_f32_16x16x32_bf16(wf[n], x01, c01[n], 0, 0, 0);
            c10[n] = __builtin_amdgcn_mfma_f32_16x16x32_bf16(wf[n], x10, c10[n], 0, 0, 0);
            c11[n] = __builtin_amdgcn_mfma_f32_16x16x32_bf16(wf[n], x11, c11[n], 0, 0, 0);
        }
    }

    // ---- epilogue compute: bias + relu + residual (all reads before barrier)
#pragma unroll
    for (int n = 0; n < 3; ++n) {
        const int cb = nbase + n * 16 + g * 4;
        f32x4 bv = *reinterpret_cast<const f32x4*>(bias + cb);
        u16x4 r00 = *reinterpret_cast<const u16x4*>(smem + LDSOFF(p0 + 1, cb * 2));
        u16x4 r01 = *reinterpret_cast<const u16x4*>(smem + LDSOFF(p1 + 1, cb * 2));
        u16x4 r10 = *reinterpret_cast<const u16x4*>(x1r0 + cb);
        u16x4 r11 = *reinterpret_cast<const u16x4*>(x1r1 + cb);
#pragma unroll
        for (int ri = 0; ri < 4; ++ri) {
            c00[n][ri] = fmaxf(c00[n][ri] + bv[ri], 0.f) + b2f(r00[ri]);
            c01[n][ri] = fmaxf(c01[n][ri] + bv[ri], 0.f) + b2f(r01[ri]);
            c10[n][ri] = fmaxf(c10[n][ri] + bv[ri], 0.f) + b2f(r10[ri]);
            c11[n][ri] = fmaxf(c11[n][ri] + bv[ri], 0.f) + b2f(r11[ri]);
        }
    }
    __syncthreads();

    // ---- plane0 out rows (reuse X region, rows 0..63)
#pragma unroll
    for (int n = 0; n < 3; ++n) {
        const int cb2 = (nbase + n * 16 + g * 4) * 2;
        u16x4 o0, o1;
#pragma unroll
        for (int ri = 0; ri < 4; ++ri) { o0[ri] = f2b(c00[n][ri]); o1[ri] = f2b(c01[n][ri]); }
        *reinterpret_cast<u16x4*>(smem + LDSOFF(p0, cb2)) = o0;
        *reinterpret_cast<u16x4*>(smem + LDSOFF(p1, cb2)) = o1;
    }
    __syncthreads();
    // scatter plane0 with scramble permutation
    for (int idx = tid; idx < 64 * 48; idx += 1024) {
        int rr = idx / 48, cg = idx % 48;
        int j = j0 + rr;
        if (j > 8190) continue;
        uint4 val = *reinterpret_cast<uint4*>(smem + LDSOFF(rr, cg * 16));
        int pt = (j & 1) ? ((j + NPOS) >> 1) : ((j >> 1) + 1);
        *reinterpret_cast<uint4*>(Xout + xbase + (size_t)pt * 2 * EMB + cg * 8) = val;
        if (j == 0)
            *reinterpret_cast<uint4*>(Xout + xbase + (size_t)8192 * 2 * EMB + cg * 8) = val;
        if (j == 8189)
            *reinterpret_cast<uint4*>(Xout + xbase + cg * 8) = val;
    }
    __syncthreads();
    // ---- plane1 out rows
#pragma unroll
    for (int n = 0; n < 3; ++n) {
        const int cb2 = (nbase + n * 16 + g * 4) * 2;
        u16x4 o0, o1;
#pragma unroll
        for (int ri = 0; ri < 4; ++ri) { o0[ri] = f2b(c10[n][ri]); o1[ri] = f2b(c11[n][ri]); }
        *reinterpret_cast<u16x4*>(smem + LDSOFF(p0, cb2)) = o0;
        *reinterpret_cast<u16x4*>(smem + LDSOFF(p1, cb2)) = o1;
    }
    __syncthreads();
    // scatter plane1
    for (int idx = tid; idx < 64 * 48; idx += 1024) {
        int rr = idx / 48, cg = idx % 48;
        int j = j0 + rr;
        if (j > 8190) continue;
        uint4 val = *reinterpret_cast<uint4*>(smem + LDSOFF(rr, cg * 16));
        int pt = (j & 1) ? ((j + NPOS) >> 1) : ((j >> 1) + 1);
        *reinterpret_cast<uint4*>(Xout + xbase + ((size_t)pt * 2 + 1) * EMB + cg * 8) = val;
        if (j == 0)
            *reinterpret_cast<uint4*>(Xout + xbase + ((size_t)8192 * 2 + 1) * EMB + cg * 8) = val;
        if (j == 8189)
            *reinterpret_cast<uint4*>(Xout + xbase + (size_t)EMB + cg * 8) = val;
    }
}

// ---- finalize: 13th scramble composed with slice -> out[j] = scan-buffer position (2j+1)
__global__ void finalize(const unsigned short* __restrict__ X, float* __restrict__ out) {
    int idx = blockIdx.x * blockDim.x + threadIdx.x;
    const int total = BATCH * 4096 * 48;
    if (idx >= total) return;
    int dg = idx % 48; int t = idx / 48;
    int j = t % 4096; int b = t / 4096;
    int d0 = dg * 8;
    size_t src0 = ((size_t)b * NPOS + (2 * j + 1)) * 2 * EMB + d0;
    size_t o0 = ((size_t)b * 4096 + j) * EMB + d0;
    size_t o1 = o0 + (size_t)BATCH * 4096 * EMB;
    float v0[8], v1[8];
#pragma unroll
    for (int e = 0; e < 8; ++e) { v0[e] = b2f(X[src0 + e]); v1[e] = b2f(X[src0 + EMB + e]); }
    *reinterpret_cast<float4*>(out + o0)     = *reinterpret_cast<float4*>(&v0[0]);
    *reinterpret_cast<float4*>(out + o0 + 4) = *reinterpret_cast<float4*>(&v0[4]);
    *reinterpret_cast<float4*>(out + o1)     = *reinterpret_cast<float4*>(&v1[0]);
    *reinterpret_cast<float4*>(out + o1 + 4) = *reinterpret_cast<float4*>(&v1[4]);
}

extern "C" void kernel_launch(void* const* d_in, const int* in_sizes, int n_in,
                              void* d_out, int out_size, void* d_ws, size_t ws_size,
                              hipStream_t stream) {
    const float* embs = (const float*)d_in[0];
    const float* mask = (const float*)d_in[1];
    const float* wl   = (const float*)d_in[2];
    const float* wc   = (const float*)d_in[3];
    const float* wr   = (const float*)d_in[4];
    const float* bias = (const float*)d_in[5];

    const size_t XELEMS = (size_t)BATCH * NPOS * 2 * EMB;    // 25,168,896
    unsigned short* X0 = (unsigned short*)d_ws;
    unsigned short* X1 = X0 + XELEMS;
    unsigned short* W  = X1 + XELEMS;                         // 12*36*24*64*8 elems

    {
        int total = LAYERS * 36 * 24 * 64;
        w_prep<<<(total + 255) / 256, 256, 0, stream>>>(wl, wc, wr, W);
    }
    {
        int total = BATCH * NPOS * (EMB / 8);
        x_init<<<(total + 255) / 256, 256, 0, stream>>>(embs, mask, X0);
    }
    unsigned short* bufs[2] = { X0, X1 };
    for (int l = 0; l < LAYERS; ++l) {
        layer_k<<<dim3(128, BATCH), 1024, 0, stream>>>(
            bufs[l & 1], bufs[(l + 1) & 1],
            W + (size_t)l * 36 * 24 * 64 * 8, bias + (size_t)l * EMB);
    }
    {
        int total = BATCH * 4096 * 48;
        finalize<<<(total + 255) / 256, 256, 0, stream>>>(bufs[0], (float*)d_out);
    }
}